// Round 7
// baseline (823.608 us; speedup 1.0000x reference)
//
#include <hip/hip_runtime.h>
#include <hip/hip_bf16.h>
#include <type_traits>
#include <math.h>

typedef __attribute__((ext_vector_type(8))) short bf16x8;
typedef __attribute__((ext_vector_type(4))) float f32x4;

typedef __attribute__((address_space(3))) char       lds_char;
typedef const __attribute__((address_space(1))) char g_char;

// ---------------- helpers ----------------
__device__ __forceinline__ float bf2f(unsigned int u16) {
    union { unsigned int i; float f; } x; x.i = (u16 & 0xffffu) << 16; return x.f;
}
__device__ __forceinline__ unsigned int f2bf(float f) {
    union { float f; unsigned int i; } x; x.f = f;
    unsigned int i = x.i;
    unsigned int r = i + 0x7fffu + ((i >> 16) & 1u);
    return r >> 16; // RNE
}

#define SLOPE 0.2f

// ---------------- CSR build ----------------
__global__ void k_hist(const int* __restrict__ tgt, int* __restrict__ cnt, int E) {
    int i = blockIdx.x * blockDim.x + threadIdx.x;
    if (i < E) atomicAdd(&cnt[tgt[i]], 1);
}

__global__ void __launch_bounds__(1024) k_scan1(const int* __restrict__ in, int* __restrict__ out,
                                                int* __restrict__ bsums, int n) {
    __shared__ int sm[1024];
    int i = blockIdx.x * 1024 + threadIdx.x;
    int v = (i < n) ? in[i] : 0;
    sm[threadIdx.x] = v; __syncthreads();
    for (int ofs = 1; ofs < 1024; ofs <<= 1) {
        int t = (threadIdx.x >= ofs) ? sm[threadIdx.x - ofs] : 0;
        __syncthreads();
        sm[threadIdx.x] += t;
        __syncthreads();
    }
    if (i < n) out[i] = sm[threadIdx.x];
    if (threadIdx.x == 1023) bsums[blockIdx.x] = sm[1023];
}

__global__ void __launch_bounds__(1024) k_scan2(int* bsums, int nb) {
    __shared__ int sm[1024];
    int v = (threadIdx.x < nb) ? bsums[threadIdx.x] : 0;
    sm[threadIdx.x] = v; __syncthreads();
    for (int ofs = 1; ofs < 1024; ofs <<= 1) {
        int t = (threadIdx.x >= ofs) ? sm[threadIdx.x - ofs] : 0;
        __syncthreads();
        sm[threadIdx.x] += t;
        __syncthreads();
    }
    if (threadIdx.x < nb) bsums[threadIdx.x] = sm[threadIdx.x] - v; // exclusive
}

__global__ void __launch_bounds__(1024) k_scan3(int* __restrict__ out1, const int* __restrict__ bsums,
                                                int* __restrict__ off0, int n) {
    int i = blockIdx.x * 1024 + threadIdx.x;
    if (i < n) out1[i] += bsums[blockIdx.x];
    if (i == 0) off0[0] = 0;
}

// packed CSR: p = {src, ew_bits}
__global__ void k_scatter(const int* __restrict__ ei, const float* __restrict__ ew,
                          const int* __restrict__ off, int* __restrict__ fill,
                          int2* __restrict__ p, int E) {
    int e = blockIdx.x * blockDim.x + threadIdx.x;
    if (e < E) {
        int s = ei[e], t = ei[E + e];
        int pos = off[t] + atomicAdd(&fill[t], 1);
        p[pos] = make_int2(s, __float_as_int(ew[e]));
    }
}

// ---------------- fused prep: WT transpose | bias table | PE projection | combo ----------------
// blocks [0,128): WT[m*256+n][k] = Wsrc_m[k][n], m order [q1 k1 v1 o1 q2 k2 v2 o2]
// blocks [128,136): biasF
// blocks [136,456): AB (row-PE proj 256 blocks, col-PE proj 64 blocks)
// blocks [456,...): combo
__global__ void __launch_bounds__(256) k_prep(const float* __restrict__ Wq, const float* __restrict__ Wk,
                                              const float* __restrict__ Wv, const float* __restrict__ Wo,
                                              unsigned short* __restrict__ WT,
                                              const float* __restrict__ bq, const float* __restrict__ bk,
                                              const float* __restrict__ bv, const float* __restrict__ bo,
                                              float* __restrict__ biasF,
                                              const float* __restrict__ W_in, float* __restrict__ AB,
                                              const int* __restrict__ ri, const int* __restrict__ ci,
                                              int* __restrict__ combo, int V) {
    __shared__ float sm[64][65];
    int blk = blockIdx.x;
    int tid = threadIdx.x;
    if (blk < 128) {
        int m = blk >> 4, t = blk & 15;
        int tr = t >> 2, tc = t & 3;   // k-tile, n-tile
        const float* srcs[4] = {Wq, Wk, Wv, Wo};
        const float* W = srcs[m & 3] + (size_t)(m >> 2) * 65536;
        for (int i = tid; i < 4096; i += 256) {
            int r = i >> 6, c = i & 63;
            sm[r][c] = W[(size_t)(tr * 64 + r) * 256 + tc * 64 + c];
        }
        __syncthreads();
        for (int i = tid; i < 4096; i += 256) {
            int n = i >> 6, k = i & 63;
            WT[(size_t)(m * 256 + tc * 64 + n) * 256 + tr * 64 + k] = (unsigned short)f2bf(sm[k][n]);
        }
    } else if (blk < 136) {
        int m = blk - 128;
        const float* srcs[4] = {bq, bk, bv, bo};
        biasF[m * 256 + tid] = srcs[m & 3][(m >> 2) * 256 + tid];
    } else if (blk < 456) {
        int b2 = blk - 136;
        bool isA = b2 < 256;
        int pos = isA ? b2 : b2 - 256;
        const float* Wb = W_in + (size_t)(isA ? 768 : 960) * 256;
        float* pe = &sm[0][0];
        if (tid < 192) {
            float div = expf(-(float)(tid & ~1) * (logf(10000.0f) / 192.0f));
            float ang = (float)pos * div;
            pe[tid] = (tid & 1) ? cosf(ang) : sinf(ang);
        }
        __syncthreads();
        float acc = 0.f;
        #pragma unroll 8
        for (int d = 0; d < 192; ++d) acc = fmaf(pe[d], Wb[d * 256 + tid], acc);
        AB[b2 * 256 + tid] = acc;
    } else {
        int v = (blk - 456) * 256 + tid;
        if (v < V) combo[v] = ri[v] * 64 + ci[v];
    }
}

// ---------------- h0 table (bf16 out): A[r]+B[c]+b_in -> LN -> ReLU ----------------
__global__ void __launch_bounds__(256) k_h0(const float* __restrict__ AB, const float* __restrict__ b_in,
                                            const float* __restrict__ g, const float* __restrict__ b,
                                            unsigned short* __restrict__ h0t) {
    int wid = threadIdx.x >> 6, lane = threadIdx.x & 63;
    int m = blockIdx.x * 4 + wid;
    int r = m >> 6, c = m & 63;
    float4 a  = ((const float4*)(AB + (size_t)r * 256))[lane];
    float4 bb = ((const float4*)(AB + (size_t)(256 + c) * 256))[lane];
    float4 bi = ((const float4*)b_in)[lane];
    float x0 = a.x + bb.x + bi.x, x1 = a.y + bb.y + bi.y;
    float x2 = a.z + bb.z + bi.z, x3 = a.w + bb.w + bi.w;
    float s = x0 + x1 + x2 + x3;
    #pragma unroll
    for (int msk = 1; msk < 64; msk <<= 1) s += __shfl_xor(s, msk);
    float mu = s * (1.f / 256.f);
    float d0 = x0 - mu, d1 = x1 - mu, d2 = x2 - mu, d3 = x3 - mu;
    float sq = d0 * d0 + d1 * d1 + d2 * d2 + d3 * d3;
    #pragma unroll
    for (int msk = 1; msk < 64; msk <<= 1) sq += __shfl_xor(sq, msk);
    float rstd = rsqrtf(sq * (1.f / 256.f) + 1e-5f);
    float4 gv = ((const float4*)g)[lane], bv = ((const float4*)b)[lane];
    float y0 = fmaxf(fmaf(d0 * rstd, gv.x, bv.x), 0.f);
    float y1 = fmaxf(fmaf(d1 * rstd, gv.y, bv.y), 0.f);
    float y2 = fmaxf(fmaf(d2 * rstd, gv.z, bv.z), 0.f);
    float y3 = fmaxf(fmaf(d3 * rstd, gv.w, bv.w), 0.f);
    uint2 o;
    o.x = f2bf(y0) | (f2bf(y1) << 16);
    o.y = f2bf(y2) | (f2bf(y3) << 16);
    *(uint2*)(h0t + (size_t)m * 256 + lane * 4) = o;
}

// ---------------- bf16 MFMA GEMM, BM=128 (for M=16K): proven R6 structure ----------------
template <typename TC, bool LEAKY>
__global__ void __launch_bounds__(256) k_mm(const unsigned short* __restrict__ A,
                                            const unsigned short* __restrict__ WT,
                                            const float* __restrict__ bias,
                                            TC* __restrict__ C, int M, int ldc) {
    __shared__ __align__(16) char AsB[16384];   // 128 rows x 64 bf16 (128B)
    __shared__ __align__(16) char BsB[16384];
    int tid = threadIdx.x;
    int R0 = blockIdx.x * 128, C0 = blockIdx.y * 128;
    int lane = tid & 63, wave = tid >> 6;
    int wr = (wave >> 1) * 64, wc = (wave & 1) * 64;
    int fr = lane & 15, fq = lane >> 4;
    f32x4 acc[4][4] = {};
    for (int k0 = 0; k0 < 256; k0 += 64) {
        #pragma unroll
        for (int it = 0; it < 4; ++it) {
            int chunk = it * 256 + tid;
            int r = chunk >> 3, cb = (chunk & 7) * 16;
            int sc = cb ^ ((r & 7) << 4);
            int gr = R0 + r;
            if (gr < M)
                __builtin_amdgcn_global_load_lds(
                    (g_char*)((const char*)(A + (size_t)gr * 256 + k0) + sc),
                    (lds_char*)(AsB + (size_t)(it * 256 + wave * 64) * 16), 16, 0, 0);
            __builtin_amdgcn_global_load_lds(
                (g_char*)((const char*)(WT + (size_t)(C0 + r) * 256 + k0) + sc),
                (lds_char*)(BsB + (size_t)(it * 256 + wave * 64) * 16), 16, 0, 0);
        }
        __syncthreads();
        #pragma unroll
        for (int ks = 0; ks < 2; ++ks) {
            bf16x8 af[4], bfv[4];
            #pragma unroll
            for (int mi = 0; mi < 4; ++mi) {
                int r = wr + mi * 16 + fr;
                int kb = ks * 64 + fq * 16;
                af[mi] = *(const bf16x8*)(AsB + r * 128 + (kb ^ ((r & 7) << 4)));
            }
            #pragma unroll
            for (int ni = 0; ni < 4; ++ni) {
                int r = wc + ni * 16 + fr;
                int kb = ks * 64 + fq * 16;
                bfv[ni] = *(const bf16x8*)(BsB + r * 128 + (kb ^ ((r & 7) << 4)));
            }
            #pragma unroll
            for (int mi = 0; mi < 4; ++mi)
                #pragma unroll
                for (int ni = 0; ni < 4; ++ni)
                    acc[mi][ni] = __builtin_amdgcn_mfma_f32_16x16x32_bf16(af[mi], bfv[ni], acc[mi][ni], 0, 0, 0);
        }
        __syncthreads();
    }
    #pragma unroll
    for (int mi = 0; mi < 4; ++mi) {
        #pragma unroll
        for (int r = 0; r < 4; ++r) {
            int row = R0 + wr + mi * 16 + fq * 4 + r;
            if (row >= M) continue;
            #pragma unroll
            for (int ni = 0; ni < 4; ++ni) {
                int col = C0 + wc + ni * 16 + fr;
                float v = acc[mi][ni][r] + bias[col];
                if (LEAKY) v = fmaxf(v, SLOPE * v);
                if constexpr (std::is_same<TC, float>::value) {
                    C[(size_t)row * ldc + col] = v;
                } else {
                    C[(size_t)row * ldc + col] = (unsigned short)f2bf(v);
                }
            }
        }
    }
}

// ---------------- bf16 MFMA GEMM, BM=256 (for M=100K): 512 thr, 8 waves 4x2, wave 64x64 ----------------
// Same proven inner pattern; halves per-output barrier/prologue overhead vs BM=128.
template <typename TC, bool LEAKY>
__global__ void __launch_bounds__(512) k_mm256(const unsigned short* __restrict__ A,
                                               const unsigned short* __restrict__ WT,
                                               const float* __restrict__ bias,
                                               TC* __restrict__ C, int M, int ldc) {
    __shared__ __align__(16) char AsB[32768];   // 256 rows x 128B
    __shared__ __align__(16) char BsB[16384];   // 128 rows x 128B
    int tid = threadIdx.x;
    int lane = tid & 63, wave = tid >> 6;
    int R0 = blockIdx.x * 256, C0 = blockIdx.y * 128;
    int wr = (wave >> 1) * 64, wc = (wave & 1) * 64;
    int fr = lane & 15, fq = lane >> 4;
    f32x4 acc[4][4] = {};
    for (int k0 = 0; k0 < 256; k0 += 64) {
        #pragma unroll
        for (int it = 0; it < 4; ++it) {
            int chunk = it * 512 + tid;                 // 2048 A-chunks of 16B
            int r = chunk >> 3, cb = (chunk & 7) * 16;
            int sc = cb ^ ((r & 7) << 4);
            int gr = R0 + r;
            if (gr < M)
                __builtin_amdgcn_global_load_lds(
                    (g_char*)((const char*)(A + (size_t)gr * 256 + k0) + sc),
                    (lds_char*)(AsB + (size_t)(it * 512 + wave * 64) * 16), 16, 0, 0);
        }
        #pragma unroll
        for (int it = 0; it < 2; ++it) {
            int chunk = it * 512 + tid;                 // 1024 B-chunks
            int r = chunk >> 3, cb = (chunk & 7) * 16;
            int sc = cb ^ ((r & 7) << 4);
            __builtin_amdgcn_global_load_lds(
                (g_char*)((const char*)(WT + (size_t)(C0 + r) * 256 + k0) + sc),
                (lds_char*)(BsB + (size_t)(it * 512 + wave * 64) * 16), 16, 0, 0);
        }
        __syncthreads();
        #pragma unroll
        for (int ks = 0; ks < 2; ++ks) {
            bf16x8 af[4], bfv[4];
            #pragma unroll
            for (int mi = 0; mi < 4; ++mi) {
                int r = wr + mi * 16 + fr;
                int kb = ks * 64 + fq * 16;
                af[mi] = *(const bf16x8*)(AsB + r * 128 + (kb ^ ((r & 7) << 4)));
            }
            #pragma unroll
            for (int ni = 0; ni < 4; ++ni) {
                int r = wc + ni * 16 + fr;
                int kb = ks * 64 + fq * 16;
                bfv[ni] = *(const bf16x8*)(BsB + r * 128 + (kb ^ ((r & 7) << 4)));
            }
            #pragma unroll
            for (int mi = 0; mi < 4; ++mi)
                #pragma unroll
                for (int ni = 0; ni < 4; ++ni)
                    acc[mi][ni] = __builtin_amdgcn_mfma_f32_16x16x32_bf16(af[mi], bfv[ni], acc[mi][ni], 0, 0, 0);
        }
        __syncthreads();
    }
    #pragma unroll
    for (int mi = 0; mi < 4; ++mi) {
        #pragma unroll
        for (int r = 0; r < 4; ++r) {
            int row = R0 + wr + mi * 16 + fq * 4 + r;
            if (row >= M) continue;
            #pragma unroll
            for (int ni = 0; ni < 4; ++ni) {
                int col = C0 + wc + ni * 16 + fr;
                float v = acc[mi][ni][r] + bias[col];
                if (LEAKY) v = fmaxf(v, SLOPE * v);
                if constexpr (std::is_same<TC, float>::value) {
                    C[(size_t)row * ldc + col] = v;
                } else {
                    C[(size_t)row * ldc + col] = (unsigned short)f2bf(v);
                }
            }
        }
    }
}

// ---------------- edge aggregation: one wave per target, 4 edges in flight ----------------
// QKV rows are [Q(256) | K(256) | V(256)] bf16, row stride 768.
// lane = quarter*16 + q; q covers dims q*16..q*16+15 (32B); head = q>>2; quarter processes edge i+quarter.
template <bool USE_COMBO>
__global__ void __launch_bounds__(256) k_edge(const int* __restrict__ off, const int2* __restrict__ pedge,
                                              const int* __restrict__ combo,
                                              const unsigned short* __restrict__ QKV,
                                              const float* __restrict__ We_l, const float* __restrict__ be_l,
                                              unsigned short* __restrict__ out, int V) {
    int wid = threadIdx.x >> 6, lane = threadIdx.x & 63;
    int t = blockIdx.x * 4 + wid;
    if (t >= V) return;
    int q = lane & 15, quarter = lane >> 4;
    int h = q >> 2;
    int krow = USE_COMBO ? combo[t] : t;
    uint4 ka = *(const uint4*)(QKV + (size_t)krow * 768 + 256 + q * 16);
    uint4 kb = *(const uint4*)(QKV + (size_t)krow * 768 + 256 + q * 16 + 8);
    float kf[16];
    kf[0] = bf2f(ka.x); kf[1] = bf2f(ka.x >> 16); kf[2] = bf2f(ka.y); kf[3] = bf2f(ka.y >> 16);
    kf[4] = bf2f(ka.z); kf[5] = bf2f(ka.z >> 16); kf[6] = bf2f(ka.w); kf[7] = bf2f(ka.w >> 16);
    kf[8] = bf2f(kb.x); kf[9] = bf2f(kb.x >> 16); kf[10] = bf2f(kb.y); kf[11] = bf2f(kb.y >> 16);
    kf[12] = bf2f(kb.z); kf[13] = bf2f(kb.z >> 16); kf[14] = bf2f(kb.w); kf[15] = bf2f(kb.w >> 16);
    float Weh = We_l[h], beh = be_l[h];
    float n[16];
    #pragma unroll
    for (int j = 0; j < 16; ++j) n[j] = 0.f;
    float den = 0.f;
    int beg = off[t], end = off[t + 1];
    for (int e0 = beg; e0 < end; e0 += 64) {
        int nrem = end - e0; if (nrem > 64) nrem = 64;
        int sv = 0; float wv = 0.f;
        if (lane < nrem) {
            int2 pr = pedge[e0 + lane];
            sv = pr.x;
            wv = __int_as_float(pr.y);
            if (USE_COMBO) sv = combo[sv];
        }
        for (int i = 0; i < nrem; i += 4) {
            int ei = i + quarter;
            bool act = ei < nrem;
            int eidx = act ? ei : (nrem - 1);
            int srow = __shfl(sv, eidx);
            float w  = __shfl(wv, eidx);
            const unsigned short* base = QKV + (size_t)srow * 768 + q * 16;
            uint4 qa = *(const uint4*)base;
            uint4 qb = *(const uint4*)(base + 8);
            uint4 va = *(const uint4*)(base + 512);
            uint4 vb = *(const uint4*)(base + 520);
            float p;
            p = bf2f(qa.x) * kf[0];
            p = fmaf(bf2f(qa.x >> 16), kf[1], p);
            p = fmaf(bf2f(qa.y),       kf[2], p);
            p = fmaf(bf2f(qa.y >> 16), kf[3], p);
            p = fmaf(bf2f(qa.z),       kf[4], p);
            p = fmaf(bf2f(qa.z >> 16), kf[5], p);
            p = fmaf(bf2f(qa.w),       kf[6], p);
            p = fmaf(bf2f(qa.w >> 16), kf[7], p);
            p = fmaf(bf2f(qb.x),       kf[8], p);
            p = fmaf(bf2f(qb.x >> 16), kf[9], p);
            p = fmaf(bf2f(qb.y),       kf[10], p);
            p = fmaf(bf2f(qb.y >> 16), kf[11], p);
            p = fmaf(bf2f(qb.z),       kf[12], p);
            p = fmaf(bf2f(qb.z >> 16), kf[13], p);
            p = fmaf(bf2f(qb.w),       kf[14], p);
            p = fmaf(bf2f(qb.w >> 16), kf[15], p);
            p += __shfl_xor(p, 1);
            p += __shfl_xor(p, 2);   // per-head dot within aligned group of 4 lanes
            float bias = fmaf(w, Weh, beh);
            bias = fmaxf(bias, SLOPE * bias);            // leaky relu (slope<1)
            float ex = act ? __expf(fmaf(p, 0.125f, bias)) : 0.f;
            den += ex;
            float cc = ex * w;
            n[0]  = fmaf(cc, bf2f(va.x),       n[0]);
            n[1]  = fmaf(cc, bf2f(va.x >> 16), n[1]);
            n[2]  = fmaf(cc, bf2f(va.y),       n[2]);
            n[3]  = fmaf(cc, bf2f(va.y >> 16), n[3]);
            n[4]  = fmaf(cc, bf2f(va.z),       n[4]);
            n[5]  = fmaf(cc, bf2f(va.z >> 16), n[5]);
            n[6]  = fmaf(cc, bf2f(va.w),       n[6]);
            n[7]  = fmaf(cc, bf2f(va.w >> 16), n[7]);
            n[8]  = fmaf(cc, bf2f(vb.x),       n[8]);
            n[9]  = fmaf(cc, bf2f(vb.x >> 16), n[9]);
            n[10] = fmaf(cc, bf2f(vb.y),       n[10]);
            n[11] = fmaf(cc, bf2f(vb.y >> 16), n[11]);
            n[12] = fmaf(cc, bf2f(vb.z),       n[12]);
            n[13] = fmaf(cc, bf2f(vb.z >> 16), n[13]);
            n[14] = fmaf(cc, bf2f(vb.w),       n[14]);
            n[15] = fmaf(cc, bf2f(vb.w >> 16), n[15]);
        }
    }
    // cross-quarter reduction (den per lane is its head's partial; n is dim partial)
    den += __shfl_xor(den, 16);
    den += __shfl_xor(den, 32);
    #pragma unroll
    for (int j = 0; j < 16; ++j) {
        n[j] += __shfl_xor(n[j], 16);
        n[j] += __shfl_xor(n[j], 32);
    }
    float inv = 1.f / (den + 1e-16f);
    if (quarter == 0) {
        uint4 o0, o1;
        o0.x = f2bf(n[0] * inv)  | (f2bf(n[1] * inv) << 16);
        o0.y = f2bf(n[2] * inv)  | (f2bf(n[3] * inv) << 16);
        o0.z = f2bf(n[4] * inv)  | (f2bf(n[5] * inv) << 16);
        o0.w = f2bf(n[6] * inv)  | (f2bf(n[7] * inv) << 16);
        o1.x = f2bf(n[8] * inv)  | (f2bf(n[9] * inv) << 16);
        o1.y = f2bf(n[10] * inv) | (f2bf(n[11] * inv) << 16);
        o1.z = f2bf(n[12] * inv) | (f2bf(n[13] * inv) << 16);
        o1.w = f2bf(n[14] * inv) | (f2bf(n[15] * inv) << 16);
        *(uint4*)(out + (size_t)t * 256 + q * 16) = o0;
        *(uint4*)(out + (size_t)t * 256 + q * 16 + 8) = o1;
    }
}

// ---------------- launcher ----------------
extern "C" void kernel_launch(void* const* d_in, const int* in_sizes, int n_in,
                              void* d_out, int out_size, void* d_ws, size_t ws_size,
                              hipStream_t stream) {
    const int*   row_idx = (const int*)d_in[0];
    const int*   col_idx = (const int*)d_in[1];
    const int*   ei      = (const int*)d_in[2];
    const float* ew      = (const float*)d_in[3];
    const float* W_in    = (const float*)d_in[4];
    const float* b_in    = (const float*)d_in[5];
    const float* ln_g    = (const float*)d_in[6];
    const float* ln_b    = (const float*)d_in[7];
    const float* Wq      = (const float*)d_in[8];
    const float* bq      = (const float*)d_in[9];
    const float* Wk      = (const float*)d_in[10];
    const float* bk      = (const float*)d_in[11];
    const float* Wv      = (const float*)d_in[12];
    const float* bv      = (const float*)d_in[13];
    const float* Wo      = (const float*)d_in[14];
    const float* bo      = (const float*)d_in[15];
    const float* We      = (const float*)d_in[16];
    const float* be      = (const float*)d_in[17];

    const int V = in_sizes[0];
    const int E = in_sizes[3];
    const int NC = 16384;

    char* w = (char*)d_ws;
    size_t o = 0;
    auto alloc = [&](size_t bytes) -> char* {
        char* p = w + o;
        o = (o + bytes + 255) & ~(size_t)255;
        return p;
    };
    int*   cnt     = (int*)alloc((size_t)V * 4);
    int*   fill    = (int*)alloc((size_t)V * 4);
    int*   csr_off = (int*)alloc((size_t)(V + 1) * 4);
    int*   bsums   = (int*)alloc(1024 * 4);
    int2*  csrP    = (int2*)alloc((size_t)E * 8);
    int*   combo   = (int*)alloc((size_t)V * 4);
    float* AB      = (float*)alloc((size_t)320 * 256 * 4);
    unsigned short* WT    = (unsigned short*)alloc((size_t)2048 * 256 * 2);
    float*          biasF = (float*)alloc((size_t)2048 * 4);
    unsigned short* h0t   = (unsigned short*)alloc((size_t)NC * 256 * 2);
    unsigned short* QKV1  = (unsigned short*)alloc((size_t)NC * 768 * 2);
    unsigned short* out_e = (unsigned short*)alloc((size_t)V * 256 * 2);
    unsigned short* h1    = (unsigned short*)alloc((size_t)V * 256 * 2);
    unsigned short* QKV2  = (unsigned short*)alloc((size_t)V * 768 * 2);

    // cnt and fill are adjacent in the carve: one memset covers both (plus align pad)
    hipMemsetAsync(cnt, 0, (size_t)2 * V * 4 + 256, stream);

    int eb = (E + 255) / 256;
    int nscan = (V + 1023) / 1024;
    int prep_blocks = 456 + (V + 255) / 256;
    k_prep<<<prep_blocks, 256, 0, stream>>>(Wq, Wk, Wv, Wo, WT, bq, bk, bv, bo, biasF,
                                            W_in, AB, row_idx, col_idx, combo, V);
    k_hist<<<eb, 256, 0, stream>>>(ei + E, cnt, E);
    k_scan1<<<nscan, 1024, 0, stream>>>(cnt, csr_off + 1, bsums, V);
    k_scan2<<<1, 1024, 0, stream>>>(bsums, nscan);
    k_scan3<<<nscan, 1024, 0, stream>>>(csr_off + 1, bsums, csr_off, V);
    k_scatter<<<eb, 256, 0, stream>>>(ei, ew, csr_off, fill, csrP, E);

    k_h0<<<NC / 4, 256, 0, stream>>>(AB, b_in, ln_g, ln_b, h0t);

    // layer 1 fused QKV GEMM on the 16K combo table (BM=128 for grid occupancy at M=16K)
    dim3 g1(NC / 128, 6);
    k_mm<unsigned short, false><<<g1, 256, 0, stream>>>(h0t, WT, biasF, QKV1, NC, 768);

    int tb = (V + 3) / 4;
    k_edge<true><<<tb, 256, 0, stream>>>(csr_off, csrP, combo, QKV1, We, be, out_e, V);

    int mb256 = (V + 255) / 256;
    dim3 go(mb256, 2);
    dim3 gqkv(mb256, 6);
    // h1 = leaky(out_e @ Wo1 + bo1)
    k_mm256<unsigned short, true><<<go, 512, 0, stream>>>(out_e, WT + (size_t)768 * 256, biasF + 768, h1, V, 256);
    // layer 2 fused QKV
    k_mm256<unsigned short, false><<<gqkv, 512, 0, stream>>>(h1, WT + (size_t)1024 * 256, biasF + 1024, QKV2, V, 768);

    k_edge<false><<<tb, 256, 0, stream>>>(csr_off, csrP, combo, QKV2, We + 4, be + 4, out_e, V);

    // final: d_out = leaky(out_e @ Wo2 + bo2) in f32
    k_mm256<float, true><<<go, 512, 0, stream>>>(out_e, WT + (size_t)1792 * 256, biasF + 1792, (float*)d_out, V, 256);
}

// Round 8
// 774.378 us; speedup vs baseline: 1.0636x; 1.0636x over previous
//
#include <hip/hip_runtime.h>
#include <hip/hip_bf16.h>
#include <type_traits>
#include <math.h>

typedef __attribute__((ext_vector_type(8))) short bf16x8;
typedef __attribute__((ext_vector_type(4))) float f32x4;

typedef __attribute__((address_space(3))) char       lds_char;
typedef const __attribute__((address_space(1))) char g_char;

// ---------------- helpers ----------------
__device__ __forceinline__ float bf2f(unsigned int u16) {
    union { unsigned int i; float f; } x; x.i = (u16 & 0xffffu) << 16; return x.f;
}
__device__ __forceinline__ unsigned int f2bf(float f) {
    union { float f; unsigned int i; } x; x.f = f;
    unsigned int i = x.i;
    unsigned int r = i + 0x7fffu + ((i >> 16) & 1u);
    return r >> 16; // RNE
}

#define SLOPE 0.2f

// ---------------- CSR build ----------------
__global__ void k_hist(const int* __restrict__ tgt, int* __restrict__ cnt, int E) {
    int i = blockIdx.x * blockDim.x + threadIdx.x;
    if (i < E) atomicAdd(&cnt[tgt[i]], 1);
}

__global__ void __launch_bounds__(1024) k_scan1(const int* __restrict__ in, int* __restrict__ out,
                                                int* __restrict__ bsums, int n) {
    __shared__ int sm[1024];
    int i = blockIdx.x * 1024 + threadIdx.x;
    int v = (i < n) ? in[i] : 0;
    sm[threadIdx.x] = v; __syncthreads();
    for (int ofs = 1; ofs < 1024; ofs <<= 1) {
        int t = (threadIdx.x >= ofs) ? sm[threadIdx.x - ofs] : 0;
        __syncthreads();
        sm[threadIdx.x] += t;
        __syncthreads();
    }
    if (i < n) out[i] = sm[threadIdx.x];
    if (threadIdx.x == 1023) bsums[blockIdx.x] = sm[1023];
}

__global__ void __launch_bounds__(1024) k_scan2(int* bsums, int nb) {
    __shared__ int sm[1024];
    int v = (threadIdx.x < nb) ? bsums[threadIdx.x] : 0;
    sm[threadIdx.x] = v; __syncthreads();
    for (int ofs = 1; ofs < 1024; ofs <<= 1) {
        int t = (threadIdx.x >= ofs) ? sm[threadIdx.x - ofs] : 0;
        __syncthreads();
        sm[threadIdx.x] += t;
        __syncthreads();
    }
    if (threadIdx.x < nb) bsums[threadIdx.x] = sm[threadIdx.x] - v; // exclusive
}

__global__ void __launch_bounds__(1024) k_scan3(int* __restrict__ out1, const int* __restrict__ bsums,
                                                int* __restrict__ off0, int n) {
    int i = blockIdx.x * 1024 + threadIdx.x;
    if (i < n) out1[i] += bsums[blockIdx.x];
    if (i == 0) off0[0] = 0;
}

// packed CSR: p = {src, ew_bits}
__global__ void k_scatter(const int* __restrict__ ei, const float* __restrict__ ew,
                          const int* __restrict__ off, int* __restrict__ fill,
                          int2* __restrict__ p, int E) {
    int e = blockIdx.x * blockDim.x + threadIdx.x;
    if (e < E) {
        int s = ei[e], t = ei[E + e];
        int pos = off[t] + atomicAdd(&fill[t], 1);
        p[pos] = make_int2(s, __float_as_int(ew[e]));
    }
}

// ---------------- fused prep: WT transpose | bias table | PE projection | combo ----------------
// blocks [0,128): WT[m*256+n][k] = Wsrc_m[k][n], m order [q1 k1 v1 o1 q2 k2 v2 o2]
// blocks [128,136): biasF
// blocks [136,456): AB (row-PE proj 256 blocks, col-PE proj 64 blocks)
// blocks [456,...): combo
__global__ void __launch_bounds__(256) k_prep(const float* __restrict__ Wq, const float* __restrict__ Wk,
                                              const float* __restrict__ Wv, const float* __restrict__ Wo,
                                              unsigned short* __restrict__ WT,
                                              const float* __restrict__ bq, const float* __restrict__ bk,
                                              const float* __restrict__ bv, const float* __restrict__ bo,
                                              float* __restrict__ biasF,
                                              const float* __restrict__ W_in, float* __restrict__ AB,
                                              const int* __restrict__ ri, const int* __restrict__ ci,
                                              int* __restrict__ combo, int V) {
    __shared__ float sm[64][65];
    int blk = blockIdx.x;
    int tid = threadIdx.x;
    if (blk < 128) {
        int m = blk >> 4, t = blk & 15;
        int tr = t >> 2, tc = t & 3;   // k-tile, n-tile
        const float* srcs[4] = {Wq, Wk, Wv, Wo};
        const float* W = srcs[m & 3] + (size_t)(m >> 2) * 65536;
        for (int i = tid; i < 4096; i += 256) {
            int r = i >> 6, c = i & 63;
            sm[r][c] = W[(size_t)(tr * 64 + r) * 256 + tc * 64 + c];
        }
        __syncthreads();
        for (int i = tid; i < 4096; i += 256) {
            int n = i >> 6, k = i & 63;
            WT[(size_t)(m * 256 + tc * 64 + n) * 256 + tr * 64 + k] = (unsigned short)f2bf(sm[k][n]);
        }
    } else if (blk < 136) {
        int m = blk - 128;
        const float* srcs[4] = {bq, bk, bv, bo};
        biasF[m * 256 + tid] = srcs[m & 3][(m >> 2) * 256 + tid];
    } else if (blk < 456) {
        int b2 = blk - 136;
        bool isA = b2 < 256;
        int pos = isA ? b2 : b2 - 256;
        const float* Wb = W_in + (size_t)(isA ? 768 : 960) * 256;
        float* pe = &sm[0][0];
        if (tid < 192) {
            float div = expf(-(float)(tid & ~1) * (logf(10000.0f) / 192.0f));
            float ang = (float)pos * div;
            pe[tid] = (tid & 1) ? cosf(ang) : sinf(ang);
        }
        __syncthreads();
        float acc = 0.f;
        #pragma unroll 8
        for (int d = 0; d < 192; ++d) acc = fmaf(pe[d], Wb[d * 256 + tid], acc);
        AB[b2 * 256 + tid] = acc;
    } else {
        int v = (blk - 456) * 256 + tid;
        if (v < V) combo[v] = ri[v] * 64 + ci[v];
    }
}

// ---------------- h0 table (bf16 out): A[r]+B[c]+b_in -> LN -> ReLU ----------------
__global__ void __launch_bounds__(256) k_h0(const float* __restrict__ AB, const float* __restrict__ b_in,
                                            const float* __restrict__ g, const float* __restrict__ b,
                                            unsigned short* __restrict__ h0t) {
    int wid = threadIdx.x >> 6, lane = threadIdx.x & 63;
    int m = blockIdx.x * 4 + wid;
    int r = m >> 6, c = m & 63;
    float4 a  = ((const float4*)(AB + (size_t)r * 256))[lane];
    float4 bb = ((const float4*)(AB + (size_t)(256 + c) * 256))[lane];
    float4 bi = ((const float4*)b_in)[lane];
    float x0 = a.x + bb.x + bi.x, x1 = a.y + bb.y + bi.y;
    float x2 = a.z + bb.z + bi.z, x3 = a.w + bb.w + bi.w;
    float s = x0 + x1 + x2 + x3;
    #pragma unroll
    for (int msk = 1; msk < 64; msk <<= 1) s += __shfl_xor(s, msk);
    float mu = s * (1.f / 256.f);
    float d0 = x0 - mu, d1 = x1 - mu, d2 = x2 - mu, d3 = x3 - mu;
    float sq = d0 * d0 + d1 * d1 + d2 * d2 + d3 * d3;
    #pragma unroll
    for (int msk = 1; msk < 64; msk <<= 1) sq += __shfl_xor(sq, msk);
    float rstd = rsqrtf(sq * (1.f / 256.f) + 1e-5f);
    float4 gv = ((const float4*)g)[lane], bv = ((const float4*)b)[lane];
    float y0 = fmaxf(fmaf(d0 * rstd, gv.x, bv.x), 0.f);
    float y1 = fmaxf(fmaf(d1 * rstd, gv.y, bv.y), 0.f);
    float y2 = fmaxf(fmaf(d2 * rstd, gv.z, bv.z), 0.f);
    float y3 = fmaxf(fmaf(d3 * rstd, gv.w, bv.w), 0.f);
    uint2 o;
    o.x = f2bf(y0) | (f2bf(y1) << 16);
    o.y = f2bf(y2) | (f2bf(y3) << 16);
    *(uint2*)(h0t + (size_t)m * 256 + lane * 4) = o;
}

// ---------------- bf16 MFMA GEMM (R6-proven): BM=BN=128, BK=64, 4 waves 2x2, 64x64/wave ----------------
// global_load_lds(16B) staging; linear LDS dest + pre-XOR-swizzled global source (byte ^= (r&7)<<4);
// ds_read_b128 applies the same XOR -> 2-way bank conflicts (free).
template <typename TC, bool LEAKY>
__global__ void __launch_bounds__(256) k_mm(const unsigned short* __restrict__ A,
                                            const unsigned short* __restrict__ WT,
                                            const float* __restrict__ bias,
                                            TC* __restrict__ C, int M, int ldc) {
    __shared__ __align__(16) char AsB[16384];   // 128 rows x 64 bf16 (128B)
    __shared__ __align__(16) char BsB[16384];
    int tid = threadIdx.x;
    int R0 = blockIdx.x * 128, C0 = blockIdx.y * 128;
    int lane = tid & 63, wave = tid >> 6;
    int wr = (wave >> 1) * 64, wc = (wave & 1) * 64;
    int fr = lane & 15, fq = lane >> 4;
    f32x4 acc[4][4] = {};
    for (int k0 = 0; k0 < 256; k0 += 64) {
        #pragma unroll
        for (int it = 0; it < 4; ++it) {
            int chunk = it * 256 + tid;
            int r = chunk >> 3, cb = (chunk & 7) * 16;
            int sc = cb ^ ((r & 7) << 4);
            int gr = R0 + r;
            if (gr < M)
                __builtin_amdgcn_global_load_lds(
                    (g_char*)((const char*)(A + (size_t)gr * 256 + k0) + sc),
                    (lds_char*)(AsB + (size_t)(it * 256 + wave * 64) * 16), 16, 0, 0);
            __builtin_amdgcn_global_load_lds(
                (g_char*)((const char*)(WT + (size_t)(C0 + r) * 256 + k0) + sc),
                (lds_char*)(BsB + (size_t)(it * 256 + wave * 64) * 16), 16, 0, 0);
        }
        __syncthreads();
        #pragma unroll
        for (int ks = 0; ks < 2; ++ks) {
            bf16x8 af[4], bfv[4];
            #pragma unroll
            for (int mi = 0; mi < 4; ++mi) {
                int r = wr + mi * 16 + fr;
                int kb = ks * 64 + fq * 16;
                af[mi] = *(const bf16x8*)(AsB + r * 128 + (kb ^ ((r & 7) << 4)));
            }
            #pragma unroll
            for (int ni = 0; ni < 4; ++ni) {
                int r = wc + ni * 16 + fr;
                int kb = ks * 64 + fq * 16;
                bfv[ni] = *(const bf16x8*)(BsB + r * 128 + (kb ^ ((r & 7) << 4)));
            }
            #pragma unroll
            for (int mi = 0; mi < 4; ++mi)
                #pragma unroll
                for (int ni = 0; ni < 4; ++ni)
                    acc[mi][ni] = __builtin_amdgcn_mfma_f32_16x16x32_bf16(af[mi], bfv[ni], acc[mi][ni], 0, 0, 0);
        }
        __syncthreads();
    }
    #pragma unroll
    for (int mi = 0; mi < 4; ++mi) {
        #pragma unroll
        for (int r = 0; r < 4; ++r) {
            int row = R0 + wr + mi * 16 + fq * 4 + r;
            if (row >= M) continue;
            #pragma unroll
            for (int ni = 0; ni < 4; ++ni) {
                int col = C0 + wc + ni * 16 + fr;
                float v = acc[mi][ni][r] + bias[col];
                if (LEAKY) v = fmaxf(v, SLOPE * v);
                if constexpr (std::is_same<TC, float>::value) {
                    C[(size_t)row * ldc + col] = v;
                } else {
                    C[(size_t)row * ldc + col] = (unsigned short)f2bf(v);
                }
            }
        }
    }
}

// ---------------- edge aggregation: one wave per target, 4 edges in flight ----------------
// QKV rows are [Q(256) | K(256) | V(256)] bf16, row stride 768.
// lane = quarter*16 + q; q covers dims q*16..q*16+15 (32B); head = q>>2; quarter processes edge i+quarter.
template <bool USE_COMBO>
__global__ void __launch_bounds__(256) k_edge(const int* __restrict__ off, const int2* __restrict__ pedge,
                                              const int* __restrict__ combo,
                                              const unsigned short* __restrict__ QKV,
                                              const float* __restrict__ We_l, const float* __restrict__ be_l,
                                              unsigned short* __restrict__ out, int V) {
    int wid = threadIdx.x >> 6, lane = threadIdx.x & 63;
    int t = blockIdx.x * 4 + wid;
    if (t >= V) return;
    int q = lane & 15, quarter = lane >> 4;
    int h = q >> 2;
    int krow = USE_COMBO ? combo[t] : t;
    uint4 ka = *(const uint4*)(QKV + (size_t)krow * 768 + 256 + q * 16);
    uint4 kb = *(const uint4*)(QKV + (size_t)krow * 768 + 256 + q * 16 + 8);
    float kf[16];
    kf[0] = bf2f(ka.x); kf[1] = bf2f(ka.x >> 16); kf[2] = bf2f(ka.y); kf[3] = bf2f(ka.y >> 16);
    kf[4] = bf2f(ka.z); kf[5] = bf2f(ka.z >> 16); kf[6] = bf2f(ka.w); kf[7] = bf2f(ka.w >> 16);
    kf[8] = bf2f(kb.x); kf[9] = bf2f(kb.x >> 16); kf[10] = bf2f(kb.y); kf[11] = bf2f(kb.y >> 16);
    kf[12] = bf2f(kb.z); kf[13] = bf2f(kb.z >> 16); kf[14] = bf2f(kb.w); kf[15] = bf2f(kb.w >> 16);
    float Weh = We_l[h], beh = be_l[h];
    float n[16];
    #pragma unroll
    for (int j = 0; j < 16; ++j) n[j] = 0.f;
    float den = 0.f;
    int beg = off[t], end = off[t + 1];
    for (int e0 = beg; e0 < end; e0 += 64) {
        int nrem = end - e0; if (nrem > 64) nrem = 64;
        int sv = 0; float wv = 0.f;
        if (lane < nrem) {
            int2 pr = pedge[e0 + lane];
            sv = pr.x;
            wv = __int_as_float(pr.y);
            if (USE_COMBO) sv = combo[sv];
        }
        for (int i = 0; i < nrem; i += 4) {
            int ei = i + quarter;
            bool act = ei < nrem;
            int eidx = act ? ei : (nrem - 1);
            int srow = __shfl(sv, eidx);
            float w  = __shfl(wv, eidx);
            const unsigned short* base = QKV + (size_t)srow * 768 + q * 16;
            uint4 qa = *(const uint4*)base;
            uint4 qb = *(const uint4*)(base + 8);
            uint4 va = *(const uint4*)(base + 512);
            uint4 vb = *(const uint4*)(base + 520);
            float p;
            p = bf2f(qa.x) * kf[0];
            p = fmaf(bf2f(qa.x >> 16), kf[1], p);
            p = fmaf(bf2f(qa.y),       kf[2], p);
            p = fmaf(bf2f(qa.y >> 16), kf[3], p);
            p = fmaf(bf2f(qa.z),       kf[4], p);
            p = fmaf(bf2f(qa.z >> 16), kf[5], p);
            p = fmaf(bf2f(qa.w),       kf[6], p);
            p = fmaf(bf2f(qa.w >> 16), kf[7], p);
            p = fmaf(bf2f(qb.x),       kf[8], p);
            p = fmaf(bf2f(qb.x >> 16), kf[9], p);
            p = fmaf(bf2f(qb.y),       kf[10], p);
            p = fmaf(bf2f(qb.y >> 16), kf[11], p);
            p = fmaf(bf2f(qb.z),       kf[12], p);
            p = fmaf(bf2f(qb.z >> 16), kf[13], p);
            p = fmaf(bf2f(qb.w),       kf[14], p);
            p = fmaf(bf2f(qb.w >> 16), kf[15], p);
            p += __shfl_xor(p, 1);
            p += __shfl_xor(p, 2);   // per-head dot within aligned group of 4 lanes
            float bias = fmaf(w, Weh, beh);
            bias = fmaxf(bias, SLOPE * bias);            // leaky relu (slope<1)
            float ex = act ? __expf(fmaf(p, 0.125f, bias)) : 0.f;
            den += ex;
            float cc = ex * w;
            n[0]  = fmaf(cc, bf2f(va.x),       n[0]);
            n[1]  = fmaf(cc, bf2f(va.x >> 16), n[1]);
            n[2]  = fmaf(cc, bf2f(va.y),       n[2]);
            n[3]  = fmaf(cc, bf2f(va.y >> 16), n[3]);
            n[4]  = fmaf(cc, bf2f(va.z),       n[4]);
            n[5]  = fmaf(cc, bf2f(va.z >> 16), n[5]);
            n[6]  = fmaf(cc, bf2f(va.w),       n[6]);
            n[7]  = fmaf(cc, bf2f(va.w >> 16), n[7]);
            n[8]  = fmaf(cc, bf2f(vb.x),       n[8]);
            n[9]  = fmaf(cc, bf2f(vb.x >> 16), n[9]);
            n[10] = fmaf(cc, bf2f(vb.y),       n[10]);
            n[11] = fmaf(cc, bf2f(vb.y >> 16), n[11]);
            n[12] = fmaf(cc, bf2f(vb.z),       n[12]);
            n[13] = fmaf(cc, bf2f(vb.z >> 16), n[13]);
            n[14] = fmaf(cc, bf2f(vb.w),       n[14]);
            n[15] = fmaf(cc, bf2f(vb.w >> 16), n[15]);
        }
    }
    // cross-quarter reduction (den per lane is its head's partial; n is dim partial)
    den += __shfl_xor(den, 16);
    den += __shfl_xor(den, 32);
    #pragma unroll
    for (int j = 0; j < 16; ++j) {
        n[j] += __shfl_xor(n[j], 16);
        n[j] += __shfl_xor(n[j], 32);
    }
    float inv = 1.f / (den + 1e-16f);
    if (quarter == 0) {
        uint4 o0, o1;
        o0.x = f2bf(n[0] * inv)  | (f2bf(n[1] * inv) << 16);
        o0.y = f2bf(n[2] * inv)  | (f2bf(n[3] * inv) << 16);
        o0.z = f2bf(n[4] * inv)  | (f2bf(n[5] * inv) << 16);
        o0.w = f2bf(n[6] * inv)  | (f2bf(n[7] * inv) << 16);
        o1.x = f2bf(n[8] * inv)  | (f2bf(n[9] * inv) << 16);
        o1.y = f2bf(n[10] * inv) | (f2bf(n[11] * inv) << 16);
        o1.z = f2bf(n[12] * inv) | (f2bf(n[13] * inv) << 16);
        o1.w = f2bf(n[14] * inv) | (f2bf(n[15] * inv) << 16);
        *(uint4*)(out + (size_t)t * 256 + q * 16) = o0;
        *(uint4*)(out + (size_t)t * 256 + q * 16 + 8) = o1;
    }
}

// ---------------- launcher ----------------
extern "C" void kernel_launch(void* const* d_in, const int* in_sizes, int n_in,
                              void* d_out, int out_size, void* d_ws, size_t ws_size,
                              hipStream_t stream) {
    const int*   row_idx = (const int*)d_in[0];
    const int*   col_idx = (const int*)d_in[1];
    const int*   ei      = (const int*)d_in[2];
    const float* ew      = (const float*)d_in[3];
    const float* W_in    = (const float*)d_in[4];
    const float* b_in    = (const float*)d_in[5];
    const float* ln_g    = (const float*)d_in[6];
    const float* ln_b    = (const float*)d_in[7];
    const float* Wq      = (const float*)d_in[8];
    const float* bq      = (const float*)d_in[9];
    const float* Wk      = (const float*)d_in[10];
    const float* bk      = (const float*)d_in[11];
    const float* Wv      = (const float*)d_in[12];
    const float* bv      = (const float*)d_in[13];
    const float* Wo      = (const float*)d_in[14];
    const float* bo      = (const float*)d_in[15];
    const float* We      = (const float*)d_in[16];
    const float* be      = (const float*)d_in[17];

    const int V = in_sizes[0];
    const int E = in_sizes[3];
    const int NC = 16384;

    char* w = (char*)d_ws;
    size_t o = 0;
    auto alloc = [&](size_t bytes) -> char* {
        char* p = w + o;
        o = (o + bytes + 255) & ~(size_t)255;
        return p;
    };
    int*   cnt     = (int*)alloc((size_t)V * 4);
    int*   fill    = (int*)alloc((size_t)V * 4);
    int*   csr_off = (int*)alloc((size_t)(V + 1) * 4);
    int*   bsums   = (int*)alloc(1024 * 4);
    int2*  csrP    = (int2*)alloc((size_t)E * 8);
    int*   combo   = (int*)alloc((size_t)V * 4);
    float* AB      = (float*)alloc((size_t)320 * 256 * 4);
    unsigned short* WT    = (unsigned short*)alloc((size_t)2048 * 256 * 2);
    float*          biasF = (float*)alloc((size_t)2048 * 4);
    unsigned short* h0t   = (unsigned short*)alloc((size_t)NC * 256 * 2);
    unsigned short* QKV1  = (unsigned short*)alloc((size_t)NC * 768 * 2);
    unsigned short* out_e = (unsigned short*)alloc((size_t)V * 256 * 2);
    unsigned short* h1    = (unsigned short*)alloc((size_t)V * 256 * 2);
    unsigned short* QKV2  = (unsigned short*)alloc((size_t)V * 768 * 2);

    // cnt and fill are adjacent in the carve: one memset covers both (plus align pad)
    hipMemsetAsync(cnt, 0, (size_t)2 * V * 4 + 256, stream);

    int eb = (E + 255) / 256;
    int nscan = (V + 1023) / 1024;
    int prep_blocks = 456 + (V + 255) / 256;
    k_prep<<<prep_blocks, 256, 0, stream>>>(Wq, Wk, Wv, Wo, WT, bq, bk, bv, bo, biasF,
                                            W_in, AB, row_idx, col_idx, combo, V);
    k_hist<<<eb, 256, 0, stream>>>(ei + E, cnt, E);
    k_scan1<<<nscan, 1024, 0, stream>>>(cnt, csr_off + 1, bsums, V);
    k_scan2<<<1, 1024, 0, stream>>>(bsums, nscan);
    k_scan3<<<nscan, 1024, 0, stream>>>(csr_off + 1, bsums, csr_off, V);
    k_scatter<<<eb, 256, 0, stream>>>(ei, ew, csr_off, fill, csrP, E);

    k_h0<<<NC / 4, 256, 0, stream>>>(AB, b_in, ln_g, ln_b, h0t);

    // layer 1 fused QKV GEMM on the 16K combo table
    dim3 g1(NC / 128, 6);
    k_mm<unsigned short, false><<<g1, 256, 0, stream>>>(h0t, WT, biasF, QKV1, NC, 768);

    int tb = (V + 3) / 4;
    k_edge<true><<<tb, 256, 0, stream>>>(csr_off, csrP, combo, QKV1, We, be, out_e, V);

    int mb = (V + 127) / 128;
    dim3 go(mb, 2);
    dim3 gqkv(mb, 6);
    // h1 = leaky(out_e @ Wo1 + bo1)
    k_mm<unsigned short, true><<<go, 256, 0, stream>>>(out_e, WT + (size_t)768 * 256, biasF + 768, h1, V, 256);
    // layer 2 fused QKV
    k_mm<unsigned short, false><<<gqkv, 256, 0, stream>>>(h1, WT + (size_t)1024 * 256, biasF + 1024, QKV2, V, 768);

    k_edge<false><<<tb, 256, 0, stream>>>(csr_off, csrP, combo, QKV2, We + 4, be + 4, out_e, V);

    // final: d_out = leaky(out_e @ Wo2 + bo2) in f32
    k_mm<float, true><<<go, 256, 0, stream>>>(out_e, WT + (size_t)1792 * 256, biasF + 1792, (float*)d_out, V, 256);
}